// Round 3
// baseline (220.765 us; speedup 1.0000x reference)
//
#include <hip/hip_runtime.h>
#include <math.h>

// Capsule dynamic routing, MI355X. Round 8: kill the LDS V-broadcast.
// R7 post-mortem: phase-1 V reads from LDS were 164KB/block (~13us/dispatch of
// LDS BW) + 3 VALU addr math per read -> VALU 45%, latency-bound. R8: TROW=64,
// wave = k-quarter, lane = row -> V reads are wave-uniform s_load_dwordx16
// (SMEM pipe, zero LDS/VALU cost); u stays in swizzled LDS (XOR commutes with
// the quad base so u-register indexing is static). Phase-1 cross-wave fold via
// LDS float atomics into Pl[10][64] (2.5KB). LDS 39.7KB -> 4 blocks/CU.
// Phase-2 swizzle math is compile-time (chalf^ri, ri unrolled).

#define BATCH 64
#define NN    2048
#define KD    128
#define JCAP  10
#define DCAP  16
#define JDIM  160
#define EPSQ  1e-7f
#define NT    32      // tiles of TROW rows
#define TROW  64
#define GSTR  132     // padded k-stride of G in LDS

// ws layout (floats): Op[64][32][160] @0 ; V[64][10][128] @327680
#define WS_OP 0
#define WS_V  (BATCH * NT * JDIM)

__device__ __forceinline__ void gload16(const float* g, void* l) {
  __builtin_amdgcn_global_load_lds(
      (const __attribute__((address_space(1))) void*)g,
      (__attribute__((address_space(3))) void*)l, 16, 0, 0);
}

// ---- K1: iteration 0 (c uniform 0.1): per-tile colsum -> fold through W ----
__global__ __launch_bounds__(256) void f_iter0(const float* __restrict__ u,
                                               const float* __restrict__ W,
                                               float* __restrict__ Op) {
  const int b = blockIdx.y, tile = blockIdx.x, t = threadIdx.x;
  __shared__ __align__(16) float4 red[256];
  __shared__ float S_s[KD];
  const int c = t & 31, rg = t >> 5;        // 8 row-groups x 8 rows
  const float* p = u + (((size_t)(b * NN + tile * TROW + rg * 8)) << 7) + (c << 2);
  float4 a = make_float4(0.f, 0.f, 0.f, 0.f);
#pragma unroll
  for (int r = 0; r < 8; ++r) {
    const float4 w4 = *(const float4*)(p + ((size_t)r << 7));
    a.x += w4.x; a.y += w4.y; a.z += w4.z; a.w += w4.w;
  }
  red[t] = a;
  __syncthreads();
  if (t < 32) {
    float4 s4 = red[t];
#pragma unroll
    for (int g = 1; g < 8; ++g) {
      const float4 w4 = red[g * 32 + t];
      s4.x += w4.x; s4.y += w4.y; s4.z += w4.z; s4.w += w4.w;
    }
    s4.x *= 0.1f; s4.y *= 0.1f; s4.z *= 0.1f; s4.w *= 0.1f;
    *(float4*)&S_s[t * 4] = s4;              // G[j][k] = 0.1*S[k] for all j
  }
  __syncthreads();
  if (t < JDIM) {
    float acc = 0.f;
#pragma unroll 4
    for (int k = 0; k < KD; ++k) acc += S_s[k] * W[k * JDIM + t];
    Op[((size_t)(b * NT) + tile) * JDIM + t] = acc;
  }
}

// ---- K2/K4: fold Op -> o[b,j,:] -> V[b,j,:] ; grid (10, 64), 128 thr ----
__global__ __launch_bounds__(128) void f_makeV(const float* __restrict__ Op,
                                               const float* __restrict__ W,
                                               float* __restrict__ V) {
  const int j = blockIdx.x, b = blockIdx.y, t = threadIdx.x;
  __shared__ float o_s[DCAP];
  if (t < DCAP) {
    float s = 0.f;
    const float* p = Op + (size_t)b * NT * JDIM + j * DCAP + t;
#pragma unroll
    for (int tl = 0; tl < NT; ++tl) s += p[tl * JDIM];
    o_s[t] = s;
  }
  __syncthreads();
  const float* wp = W + t * JDIM + j * DCAP;   // t = k (0..127)
  float acc = 0.f;
#pragma unroll
  for (int d = 0; d < DCAP; ++d) acc += wp[d] * o_s[d];
  V[((size_t)(b * JCAP + j) << 7) + t] = acc;
}

// ---- K3/K5: full routing iteration: logits -> softmax -> G -> fold W ----
__global__ __launch_bounds__(256) void f_route(const float* __restrict__ u,
                                               const float* __restrict__ V,
                                               const float* __restrict__ W,
                                               float* __restrict__ Op) {
  const int b = blockIdx.y, tile = blockIdx.x, t = threadIdx.x;
  const int r0 = tile * TROW;
  __shared__ __align__(16) float4 u4[TROW * 32];    // 32 KB, XOR-swizzled
  __shared__ __align__(16) float Cs[JCAP][TROW];    // 2.5 KB
  __shared__ __align__(16) float GpPl[JCAP * GSTR]; // 5.28 KB; ph1: Pl[j][64]

  // stage u tile -> LDS (swizzled source, linear dest); zero Pl meanwhile
  {
    const float* ub = u + (((size_t)(b * NN + r0)) << 7);
    const int wbase = t & 192;                      // wave base within block
#pragma unroll
    for (int p = 0; p < 8; ++p) {
      const int s = p * 256 + t;
      const int r = s >> 5, csl = s & 31;
      const int c = csl ^ (r & 7);                  // involution
      gload16(ub + (((size_t)r) << 7) + (c << 2), &u4[p * 256 + wbase]);
    }
  }
  for (int i = t; i < JCAP * TROW; i += 256) GpPl[i] = 0.f;
  __syncthreads();   // drains vmcnt

  // phase 1: logits. wave = k-quarter (V via s_loads), lane = row.
  {
    const int r = t & 63, rx = r & 7;
    const int q = __builtin_amdgcn_readfirstlane(t >> 6);
    const int ubase = (r << 5) + (q << 3);
    float4 ur[8];
#pragma unroll
    for (int c = 0; c < 8; ++c) ur[c] = u4[ubase + (c ^ rx)];
    const int voff = __builtin_amdgcn_readfirstlane(b * JCAP * KD + (q << 5));
    const float* vp = V + voff;                     // wave-uniform -> s_loads
    float acc[JCAP];
#pragma unroll
    for (int j = 0; j < JCAP; ++j) {
      const float* vj = vp + (j << 7);
      float a = 0.f;
#pragma unroll
      for (int c = 0; c < 8; ++c) {
        const float4 vv = *(const float4*)(vj + (c << 2));
        a += ur[c].x * vv.x + ur[c].y * vv.y + ur[c].z * vv.z + ur[c].w * vv.w;
      }
      acc[j] = a;
    }
#pragma unroll
    for (int j = 0; j < JCAP; ++j) atomicAdd(&GpPl[j * TROW + r], acc[j]);
  }
  __syncthreads();
  if (t < TROW) {                                   // softmax over j (1 wave)
    float lg[JCAP];
    float m = -1e30f;
#pragma unroll
    for (int j = 0; j < JCAP; ++j) {
      lg[j] = GpPl[j * TROW + t]; m = fmaxf(m, lg[j]);
    }
    float ss = 0.f;
#pragma unroll
    for (int j = 0; j < JCAP; ++j) { lg[j] = __expf(lg[j] - m); ss += lg[j]; }
    const float inv = 1.f / ss;
#pragma unroll
    for (int j = 0; j < JCAP; ++j) Cs[j][t] = lg[j] * inv;
  }
  __syncthreads();

  // phase 2: G[j][k] = sum_r c[j][r]*u[r][k]. Wave owns a j-subset over ALL
  // rows. lane = k-pair; swizzle term chalf^ri is compile-time per ri.
  {
    const int w = t >> 6, l = t & 63;
    const int j0 = (w < 2) ? 3 * w : 2 * w + 2;     // {0,3,6,8}
    const int jn = (w < 2) ? 3 : 2;                 // {3,3,2,2}
    const int chalf = l >> 1, cin = (l & 1) << 1;   // k = 2*l
    float g0[3], g1[3];
#pragma unroll
    for (int jj = 0; jj < 3; ++jj) { g0[jj] = 0.f; g1[jj] = 0.f; }
#pragma unroll
    for (int o = 0; o < 8; ++o) {                   // row octaves
      float ua[8], uc[8];
#pragma unroll
      for (int ri = 0; ri < 8; ++ri) {
        const int r = o * 8 + ri;
        const float2 uu2 =
            *(const float2*)((const float*)&u4[(r << 5) + (chalf ^ ri)] + cin);
        ua[ri] = uu2.x; uc[ri] = uu2.y;
      }
#pragma unroll
      for (int jj = 0; jj < 3; ++jj) {
        if (jj < jn) {
          const float4 cA = *(const float4*)&Cs[j0 + jj][o * 8];
          const float4 cB = *(const float4*)&Cs[j0 + jj][o * 8 + 4];
          g0[jj] += cA.x * ua[0] + cA.y * ua[1] + cA.z * ua[2] + cA.w * ua[3]
                  + cB.x * ua[4] + cB.y * ua[5] + cB.z * ua[6] + cB.w * ua[7];
          g1[jj] += cA.x * uc[0] + cA.y * uc[1] + cA.z * uc[2] + cA.w * uc[3]
                  + cB.x * uc[4] + cB.y * uc[5] + cB.z * uc[6] + cB.w * uc[7];
        }
      }
    }
#pragma unroll
    for (int jj = 0; jj < 3; ++jj)
      if (jj < jn)
        *(float2*)&GpPl[(j0 + jj) * GSTR + 2 * l] = make_float2(g0[jj], g1[jj]);
  }
  __syncthreads();
  // fold G through W -> per-tile o partials (GSTR pad spreads j over banks)
  if (t < JDIM) {
    const int j = t >> 4;
    const float* gj = GpPl + j * GSTR;
    float acc = 0.f;
#pragma unroll 8
    for (int k = 0; k < KD; ++k) acc += gj[k] * W[k * JDIM + t];
    Op[((size_t)(b * NT) + tile) * JDIM + t] = acc;
  }
}

// ---- K6: fold Op partials, squash, store ----
__global__ __launch_bounds__(192) void f_squash(const float* __restrict__ Op,
                                                float* __restrict__ out) {
  const int b = blockIdx.x, t = threadIdx.x;
  __shared__ float o_s[JDIM];
  __shared__ float sc[JCAP];
  if (t < JDIM) {
    float s = 0.f;
    const float* p = Op + (size_t)b * NT * JDIM + t;
#pragma unroll
    for (int tl = 0; tl < NT; ++tl) s += p[tl * JDIM];
    o_s[t] = s;
  }
  __syncthreads();
  if (t < JCAP) {
    float s2 = 0.f;
#pragma unroll
    for (int d = 0; d < DCAP; ++d) { const float x = o_s[t * DCAP + d]; s2 += x * x; }
    sc[t] = s2 / ((1.f + s2) * sqrtf(s2 + EPSQ));
  }
  __syncthreads();
  if (t < JDIM) out[b * JDIM + t] = o_s[t] * sc[t >> 4];
}

extern "C" void kernel_launch(void* const* d_in, const int* in_sizes, int n_in,
                              void* d_out, int out_size, void* d_ws, size_t ws_size,
                              hipStream_t stream) {
  const float* u = (const float*)d_in[0];   // (64,2048,128) fp32
  const float* W = (const float*)d_in[1];   // (128,160) fp32
  float* out = (float*)d_out;               // (64,10,16) fp32
  float* ws  = (float*)d_ws;

  float* Op = ws + WS_OP;
  float* V  = ws + WS_V;
  f_iter0 <<<dim3(NT, BATCH), 256, 0, stream>>>(u, W, Op);
  f_makeV <<<dim3(JCAP, BATCH), 128, 0, stream>>>(Op, W, V);
  f_route <<<dim3(NT, BATCH), 256, 0, stream>>>(u, V, W, Op);
  f_makeV <<<dim3(JCAP, BATCH), 128, 0, stream>>>(Op, W, V);
  f_route <<<dim3(NT, BATCH), 256, 0, stream>>>(u, V, W, Op);
  f_squash<<<BATCH, 192, 0, stream>>>(Op, out);
}